// Round 2
// 1049.297 us; speedup vs baseline: 1.0599x; 1.0599x over previous
//
#include <hip/hip_runtime.h>

// bf16 storage type = ushort (raw bits); avoids hip_bf16.h dependency.
typedef __bf16 bf16x8 __attribute__((ext_vector_type(8)));
typedef float f32x4 __attribute__((ext_vector_type(4)));

#define MFMA16(a, b, c) __builtin_amdgcn_mfma_f32_16x16x32_bf16((a), (b), (c), 0, 0, 0)

__device__ __forceinline__ unsigned short f2bf(float f) {
    // round-to-nearest-even bf16 (finite inputs)
    unsigned int u = __float_as_uint(f);
    u += 0x7fffu + ((u >> 16) & 1u);
    return (unsigned short)(u >> 16);
}

__device__ __forceinline__ void gload16(const unsigned short* g, unsigned short* l) {
    // async global->LDS, 16B per lane; LDS dest = wave-uniform base + lane*16
    __builtin_amdgcn_global_load_lds(
        (__attribute__((address_space(1))) void*)(void*)g,
        (__attribute__((address_space(3))) void*)(void*)l,
        16, 0, 0);
}

// BK=64 tile: rows x 64 bf16 = 128 B/row = 8 chunks of 16 B.
// Swizzle: global chunk (r,c) stored at LDS position (r, c ^ (r&7)).
// Reader at fixed (k-half, quad) spreads uniformly over all 8 bank-quads
// across 16 consecutive rows -> conflict-free (verified: 0 conflicts).

// frag load: 4x ds_read_b128 from a swizzled [rows][64] bf16 tile
__device__ __forceinline__ void ld_frag4(const unsigned short* base, int w0, int h,
                                         int l16, int quad, bf16x8* f) {
#pragma unroll
    for (int i = 0; i < 4; ++i) {
        const int r = w0 + i * 16 + l16;
        f[i] = *(const bf16x8*)(base + r * 64 + (((h * 4 + quad) ^ (r & 7)) * 8));
    }
}

__device__ __forceinline__ void mfma16x(const bf16x8* af, const bf16x8* bf, f32x4 (*acc)[4]) {
    __builtin_amdgcn_s_setprio(1);  // T5: favor MFMA-entering waves
#pragma unroll
    for (int i = 0; i < 4; ++i)
#pragma unroll
        for (int j = 0; j < 4; ++j) acc[i][j] = MFMA16(af[i], bf[j], acc[i][j]);
    __builtin_amdgcn_s_setprio(0);
}

#define ASM_VMCNT2 asm volatile("s_waitcnt vmcnt(2)" ::: "memory")
#define ASM_VMCNT0 asm volatile("s_waitcnt vmcnt(0)" ::: "memory")
#define ASM_LGKM0  asm volatile("s_waitcnt lgkmcnt(0)" ::: "memory")

// ---------------- prep: x fp32 -> bf16 ----------------
__global__ void cast_x_kernel(const float4* __restrict__ x, ushort4* __restrict__ xb) {
    const size_t i = (size_t)blockIdx.x * 256 + threadIdx.x;
    const float4 v = x[i];
    ushort4 o;
    o.x = f2bf(v.x); o.y = f2bf(v.y); o.z = f2bf(v.z); o.w = f2bf(v.w);
    xb[i] = o;
}

// ---------------- prep: WT[n,k] = W[k,n] + sum_r A[k,r]*B2[r,n], bf16 out ----
__global__ void prep_wT(const float* __restrict__ W, const float* __restrict__ A,
                        const float* __restrict__ B2, unsigned short* __restrict__ WT,
                        const int K, const int N) {
    __shared__ float tile[64][65];
    __shared__ float As[64][16];
    __shared__ float Bs[16][64];
    const int t = threadIdx.x;         // 256 threads
    const int k0 = blockIdx.x * 64;
    const int n0 = blockIdx.y * 64;

    for (int i = t; i < 64 * 16; i += 256)
        As[i >> 4][i & 15] = A[(size_t)(k0 + (i >> 4)) * 16 + (i & 15)];
    for (int i = t; i < 16 * 64; i += 256)
        Bs[i >> 6][i & 63] = B2[(size_t)(i >> 6) * N + n0 + (i & 63)];
    __syncthreads();

    const int c = t & 63;
    const int r0 = t >> 6;
    for (int rr = 0; rr < 64; rr += 4) {
        const int r = rr + r0;
        float v = W[(size_t)(k0 + r) * N + n0 + c];
#pragma unroll
        for (int q = 0; q < 16; ++q) v += As[r][q] * Bs[q][c];
        tile[r][c] = v;
    }
    __syncthreads();
    for (int rr = 0; rr < 64; rr += 4) {
        const int r = rr + r0;
        WT[(size_t)(n0 + r) * K + k0 + c] = f2bf(tile[c][r]);
    }
}

// ---------------- fused gate+up GEMM, 4-phase counted-vmcnt schedule ---------
// Tile 256(M) x 128(F), BK=64, 512 threads = 8 waves (4M x 2N), dbuf LDS 128KiB.
// Per K-tile, 4 phases: {gate k0 | up k0 | gate k1 | up k1}; each phase stages
// one 16-KB unit of tile t+1 (order: A-m0, A-m1, Bg, Bu) so at each counted
// vmcnt(2) the units about to be read are the OLDEST in flight; the newest
// unit (2 loads/thread) stays airborne across the barrier (T3+T4, never
// vmcnt(0) in the steady-state loop). setprio around MFMA clusters (T5).
//
// FIFO accounting (2 loads/unit/thread, in-order retire):
//   enter ph0: in-flight = Bu(t) <=2; ph0 stages A-m0(t+1) -> <=4;
//     vmcnt(2) drains oldest 2 = Bu(t)  -> ph1's Up reads safe.
//   end ph3: <=8 in flight; vmcnt(2) drains A-m0/A-m1/Bg(t+1);
//     Bu(t+1) <=2 stays airborne across the barrier.
//   LAST tile (pf=false): ph0 stages nothing, so vmcnt(2) would NOT drain
//     Bu(NT-1) -> must use vmcnt(0) there (race found in R1: absmax 0.22).
__global__ __launch_bounds__(512, 2)
void gemm_gateup(const unsigned short* __restrict__ Xb,
                 const unsigned short* __restrict__ WgT,
                 const unsigned short* __restrict__ WuT,
                 const float* __restrict__ bg, const float* __restrict__ bu,
                 unsigned short* __restrict__ X3) {
    constexpr int K = 2048, F = 8192, BK = 64, NT = K / BK;
    extern __shared__ __align__(16) unsigned short lds[];  // 128 KiB dynamic
    unsigned short* const A0 = lds;          // [2][256*64]
    unsigned short* const G0 = lds + 32768;  // [2][128*64]
    unsigned short* const U0 = lds + 49152;  // [2][128*64]

    const int tid = threadIdx.x;
    const int lane = tid & 63;
    const int wave = tid >> 6;          // 0..7
    const int wm = (wave >> 1) * 64;    // 0,64,128,192
    const int wn = (wave & 1) * 64;     // 0,64
    const int l16 = lane & 15;
    const int quad = lane >> 4;

    const int m0 = blockIdx.x * 256;
    const int n0 = blockIdx.y * 128;

    const unsigned short* Ag = Xb + (size_t)m0 * K;
    const unsigned short* Gg = WgT + (size_t)n0 * K;
    const unsigned short* Ug = WuT + (size_t)n0 * K;

    // staging: one unit = 128 rows x 64 k = 1024 chunks of 16B; 512 threads x 2.
    // LDS dest linear in chunk id (global_load_lds rule); global source column
    // carries the swizzle: col = (pos ^ (row&7)).
    int srow[2], soff[2];
#pragma unroll
    for (int j = 0; j < 2; ++j) {
        const int c = tid + j * 512;
        srow[j] = c >> 3;
        soff[j] = ((c & 7) ^ (srow[j] & 7)) * 8;
    }
    const int dst0 = tid * 8, dst1 = (tid + 512) * 8;

#define STAGE(gptr, lbase, kk, roff)                                                        \
    do {                                                                                    \
        gload16((gptr) + (size_t)(srow[0] + (roff)) * K + (kk) + soff[0], (lbase) + dst0);  \
        gload16((gptr) + (size_t)(srow[1] + (roff)) * K + (kk) + soff[1], (lbase) + dst1);  \
    } while (0)

    f32x4 accg[4][4] = {};
    f32x4 accu[4][4] = {};
    bf16x8 af[4], bfr[4];

    // prologue: tile 0 -> buf 0 (units: A-m0, A-m1, Bg, Bu)
    STAGE(Ag, A0, 0, 0);
    STAGE(Ag, A0 + 8192, 0, 128);
    STAGE(Gg, G0, 0, 0);
    STAGE(Ug, U0, 0, 0);
    ASM_VMCNT2;  // A + Bg done; Bu(0) may still fly (first read is ph1)
    __builtin_amdgcn_s_barrier();
    __builtin_amdgcn_sched_barrier(0);

    for (int t = 0; t < NT; ++t) {
        const int p = t & 1, q = p ^ 1;
        const unsigned short* Ap = A0 + p * 16384;
        const unsigned short* Gp = G0 + p * 8192;
        const unsigned short* Up = U0 + p * 8192;
        unsigned short* const Aq = A0 + q * 16384;
        unsigned short* const Gq = G0 + q * 8192;
        unsigned short* const Uq = U0 + q * 8192;
        const int kn = (t + 1) * BK;
        const bool pf = (t + 1 < NT);  // block-uniform

        // ---- ph0: gate, k-half 0 ; stage A-m0(t+1) ----
        ld_frag4(Ap, wm, 0, l16, quad, af);
        ld_frag4(Gp, wn, 0, l16, quad, bfr);
        if (pf) STAGE(Ag, Aq, kn, 0);
        __builtin_amdgcn_s_barrier();
        ASM_LGKM0;
        __builtin_amdgcn_sched_barrier(0);  // rule #18: pin MFMA after the wait
        mfma16x(af, bfr, accg);
        if (pf) {
            ASM_VMCNT2;  // Bu(t) done (read in ph1); A-m0(t+1) stays in flight
        } else {
            ASM_VMCNT0;  // last tile: nothing was staged this phase -> must
                         // drain Bu(NT-1) fully before ph1 reads it (R1 bug)
        }
        __builtin_amdgcn_s_barrier();
        __builtin_amdgcn_sched_barrier(0);

        // ---- ph1: up, k-half 0 (af reused) ; stage A-m1(t+1) ----
        ld_frag4(Up, wn, 0, l16, quad, bfr);
        if (pf) STAGE(Ag, Aq + 8192, kn, 128);
        __builtin_amdgcn_s_barrier();
        ASM_LGKM0;
        __builtin_amdgcn_sched_barrier(0);
        mfma16x(af, bfr, accu);
        __builtin_amdgcn_s_barrier();

        // ---- ph2: gate, k-half 1 ; stage Bg(t+1) ----
        ld_frag4(Ap, wm, 1, l16, quad, af);
        ld_frag4(Gp, wn, 1, l16, quad, bfr);
        if (pf) STAGE(Gg, Gq, kn, 0);
        __builtin_amdgcn_s_barrier();
        ASM_LGKM0;
        __builtin_amdgcn_sched_barrier(0);
        mfma16x(af, bfr, accg);
        __builtin_amdgcn_s_barrier();

        // ---- ph3: up, k-half 1 ; stage Bu(t+1) ----
        ld_frag4(Up, wn, 1, l16, quad, bfr);
        if (pf) STAGE(Ug, Uq, kn, 0);
        __builtin_amdgcn_s_barrier();
        ASM_LGKM0;
        __builtin_amdgcn_sched_barrier(0);
        mfma16x(af, bfr, accu);
        ASM_VMCNT2;  // A(t+1)+Bg(t+1) done (read in ph0); Bu(t+1) stays in flight
        __builtin_amdgcn_s_barrier();
        __builtin_amdgcn_sched_barrier(0);
    }
#undef STAGE

    // epilogue: C/D layout col = lane&15, row = quad*4 + reg  [m89/m91-verified]
#pragma unroll
    for (int j = 0; j < 4; ++j) {
        const int col = n0 + wn + j * 16 + l16;
        const float bgv = bg[col];
        const float buv = bu[col];
#pragma unroll
        for (int i = 0; i < 4; ++i) {
            const int rowb = m0 + wm + i * 16 + quad * 4;
#pragma unroll
            for (int r = 0; r < 4; ++r) {
                float g = accg[i][j][r] + bgv;
                float u = accu[i][j][r] + buv;
                g = g > 0.f ? g : 0.f;
                X3[(size_t)(rowb + r) * F + col] = f2bf(g * u);
            }
        }
    }
}

// ---------------- down GEMM: out = X3@WdT^T + bd, fp32 out ----------------
// X3: [M,8192] bf16, WdT: [2048,8192] bf16
__global__ __launch_bounds__(256, 3)
void gemm_down(const unsigned short* __restrict__ X3,
               const unsigned short* __restrict__ WdT,
               const float* __restrict__ bd, float* __restrict__ out) {
    constexpr int K = 8192, N = 2048;
    constexpr int BK = 64;
    __shared__ __align__(16) unsigned short As[128 * BK];
    __shared__ __align__(16) unsigned short Bs[128 * BK];

    const int tid = threadIdx.x;
    const int lane = tid & 63;
    const int wave = tid >> 6;
    const int wm = (wave >> 1) * 64;
    const int wn = (wave & 1) * 64;
    const int l16 = lane & 15;
    const int quad = lane >> 4;

    const int m0 = blockIdx.x * 128;
    const int n0 = blockIdx.y * 128;

    const unsigned short* Ag = X3 + (size_t)m0 * K;
    const unsigned short* Bgp = WdT + (size_t)n0 * K;

    int srow[4], soff[4];
#pragma unroll
    for (int j = 0; j < 4; ++j) {
        const int c = tid + j * 256;
        srow[j] = c >> 3;
        soff[j] = ((c & 7) ^ (srow[j] & 7)) * 8;
    }

    f32x4 acc[4][4] = {};

    for (int k0 = 0; k0 < K; k0 += BK) {
#pragma unroll
        for (int j = 0; j < 4; ++j)
            gload16(Ag + (size_t)srow[j] * K + k0 + soff[j], As + (tid + j * 256) * 8);
#pragma unroll
        for (int j = 0; j < 4; ++j)
            gload16(Bgp + (size_t)srow[j] * K + k0 + soff[j], Bs + (tid + j * 256) * 8);
        __syncthreads();
#pragma unroll
        for (int h = 0; h < 2; ++h) {
            bf16x8 af[4], bfr[4];
#pragma unroll
            for (int i = 0; i < 4; ++i) {
                const int ra = wm + i * 16 + l16;
                const int rb = wn + i * 16 + l16;
                const int pa = ((h * 4 + quad) ^ (ra & 7)) * 8;
                const int pb = ((h * 4 + quad) ^ (rb & 7)) * 8;
                af[i] = *(const bf16x8*)(As + ra * BK + pa);
                bfr[i] = *(const bf16x8*)(Bs + rb * BK + pb);
            }
#pragma unroll
            for (int i = 0; i < 4; ++i)
#pragma unroll
                for (int j = 0; j < 4; ++j)
                    acc[i][j] = MFMA16(af[i], bfr[j], acc[i][j]);
        }
        __syncthreads();
    }

#pragma unroll
    for (int j = 0; j < 4; ++j) {
        const int col = n0 + wn + j * 16 + l16;
        const float bdv = bd[col];
#pragma unroll
        for (int i = 0; i < 4; ++i) {
            const int rowb = m0 + wm + i * 16 + quad * 4;
#pragma unroll
            for (int r = 0; r < 4; ++r)
                out[(size_t)(rowb + r) * N + col] = acc[i][j][r] + bdv;
        }
    }
}

extern "C" void kernel_launch(void* const* d_in, const int* in_sizes, int n_in,
                              void* d_out, int out_size, void* d_ws, size_t ws_size,
                              hipStream_t stream) {
    const float* x1      = (const float*)d_in[0];
    const float* w_gate  = (const float*)d_in[1];
    const float* b_gate  = (const float*)d_in[2];
    const float* a_gate  = (const float*)d_in[3];
    const float* lb_gate = (const float*)d_in[4];
    const float* w_up    = (const float*)d_in[5];
    const float* b_up    = (const float*)d_in[6];
    const float* a_up    = (const float*)d_in[7];
    const float* lb_up   = (const float*)d_in[8];
    const float* w_down  = (const float*)d_in[9];
    const float* b_down  = (const float*)d_in[10];
    const float* a_down  = (const float*)d_in[11];
    const float* lb_down = (const float*)d_in[12];

    constexpr int M = 8192, D = 2048, F = 8192;

    // one-time: allow 128 KiB dynamic LDS for gemm_gateup (gfx950 has 160 KiB/CU)
    static bool attr_set = false;
    if (!attr_set) {
        (void)hipFuncSetAttribute((const void*)gemm_gateup,
                                  hipFuncAttributeMaxDynamicSharedMemorySize, 131072);
        attr_set = true;
    }

    // workspace layout (256 MiB total)
    char* ws = (char*)d_ws;
    unsigned short* Xb  = (unsigned short*)ws;                     // [M,D]  bf16  32 MiB
    unsigned short* WgT = (unsigned short*)(ws + 33554432ULL);     // [F,D]  bf16  32 MiB
    unsigned short* WuT = (unsigned short*)(ws + 67108864ULL);     // [F,D]  bf16  32 MiB
    unsigned short* WdT = (unsigned short*)(ws + 100663296ULL);    // [D,F]  bf16  32 MiB
    unsigned short* X3  = (unsigned short*)(ws + 134217728ULL);    // [M,F]  bf16 128 MiB

    cast_x_kernel<<<dim3((M * D) / 4 / 256), dim3(256), 0, stream>>>(
        (const float4*)x1, (ushort4*)Xb);
    prep_wT<<<dim3(D / 64, F / 64), dim3(256), 0, stream>>>(w_gate, a_gate, lb_gate, WgT, D, F);
    prep_wT<<<dim3(D / 64, F / 64), dim3(256), 0, stream>>>(w_up, a_up, lb_up, WuT, D, F);
    prep_wT<<<dim3(F / 64, D / 64), dim3(256), 0, stream>>>(w_down, a_down, lb_down, WdT, F, D);

    gemm_gateup<<<dim3(M / 256, F / 128), dim3(512), 131072, stream>>>(
        Xb, WgT, WuT, b_gate, b_up, X3);
    gemm_down<<<dim3(M / 128, D / 128), dim3(256), 0, stream>>>(
        X3, WdT, b_down, (float*)d_out);
}

// Round 3
// 1011.382 us; speedup vs baseline: 1.0997x; 1.0375x over previous
//
#include <hip/hip_runtime.h>

// bf16 storage type = ushort (raw bits); avoids hip_bf16.h dependency.
typedef __bf16 bf16x8 __attribute__((ext_vector_type(8)));
typedef float f32x4 __attribute__((ext_vector_type(4)));

#define MFMA16(a, b, c) __builtin_amdgcn_mfma_f32_16x16x32_bf16((a), (b), (c), 0, 0, 0)

__device__ __forceinline__ unsigned short f2bf(float f) {
    // round-to-nearest-even bf16 (finite inputs)
    unsigned int u = __float_as_uint(f);
    u += 0x7fffu + ((u >> 16) & 1u);
    return (unsigned short)(u >> 16);
}

__device__ __forceinline__ void gload16(const unsigned short* g, unsigned short* l) {
    // async global->LDS, 16B per lane; LDS dest = wave-uniform base + lane*16
    __builtin_amdgcn_global_load_lds(
        (__attribute__((address_space(1))) void*)(void*)g,
        (__attribute__((address_space(3))) void*)(void*)l,
        16, 0, 0);
}

// BK=64 tile: rows x 64 bf16 = 128 B/row = 8 chunks of 16 B.
// Swizzle: global chunk (r,c) stored at LDS position (r, c ^ (r&7)).
// Reader at fixed (k-half, quad) spreads uniformly over all 8 bank-quads
// across 16 consecutive rows -> conflict-free (verified: 0 conflicts).

// frag load: 4x ds_read_b128 from a swizzled [rows][64] bf16 tile
__device__ __forceinline__ void ld_frag4(const unsigned short* base, int w0, int h,
                                         int l16, int quad, bf16x8* f) {
#pragma unroll
    for (int i = 0; i < 4; ++i) {
        const int r = w0 + i * 16 + l16;
        f[i] = *(const bf16x8*)(base + r * 64 + (((h * 4 + quad) ^ (r & 7)) * 8));
    }
}

__device__ __forceinline__ void mfma16x(const bf16x8* af, const bf16x8* bf, f32x4 (*acc)[4]) {
    __builtin_amdgcn_s_setprio(1);  // T5: favor MFMA-entering waves
#pragma unroll
    for (int i = 0; i < 4; ++i)
#pragma unroll
        for (int j = 0; j < 4; ++j) acc[i][j] = MFMA16(af[i], bf[j], acc[i][j]);
    __builtin_amdgcn_s_setprio(0);
}

#define ASM_VMCNT6 asm volatile("s_waitcnt vmcnt(6)" ::: "memory")
#define ASM_VMCNT2 asm volatile("s_waitcnt vmcnt(2)" ::: "memory")
#define ASM_VMCNT0 asm volatile("s_waitcnt vmcnt(0)" ::: "memory")
#define ASM_LGKM0  asm volatile("s_waitcnt lgkmcnt(0)" ::: "memory")

// ---------------- prep: x fp32 -> bf16 ----------------
__global__ void cast_x_kernel(const float4* __restrict__ x, ushort4* __restrict__ xb) {
    const size_t i = (size_t)blockIdx.x * 256 + threadIdx.x;
    const float4 v = x[i];
    ushort4 o;
    o.x = f2bf(v.x); o.y = f2bf(v.y); o.z = f2bf(v.z); o.w = f2bf(v.w);
    xb[i] = o;
}

// ---------------- prep: WT[n,k] = W[k,n] + sum_r A[k,r]*B2[r,n], bf16 out ----
__global__ void prep_wT(const float* __restrict__ W, const float* __restrict__ A,
                        const float* __restrict__ B2, unsigned short* __restrict__ WT,
                        const int K, const int N) {
    __shared__ float tile[64][65];
    __shared__ float As[64][16];
    __shared__ float Bs[16][64];
    const int t = threadIdx.x;         // 256 threads
    const int k0 = blockIdx.x * 64;
    const int n0 = blockIdx.y * 64;

    for (int i = t; i < 64 * 16; i += 256)
        As[i >> 4][i & 15] = A[(size_t)(k0 + (i >> 4)) * 16 + (i & 15)];
    for (int i = t; i < 16 * 64; i += 256)
        Bs[i >> 6][i & 63] = B2[(size_t)(i >> 6) * N + n0 + (i & 63)];
    __syncthreads();

    const int c = t & 63;
    const int r0 = t >> 6;
    for (int rr = 0; rr < 64; rr += 4) {
        const int r = rr + r0;
        float v = W[(size_t)(k0 + r) * N + n0 + c];
#pragma unroll
        for (int q = 0; q < 16; ++q) v += As[r][q] * Bs[q][c];
        tile[r][c] = v;
    }
    __syncthreads();
    for (int rr = 0; rr < 64; rr += 4) {
        const int r = rr + r0;
        WT[(size_t)(n0 + r) * K + k0 + c] = f2bf(tile[c][r]);
    }
}

// ---------------- fused gate+up GEMM, 4-phase counted-vmcnt schedule ---------
// Tile 256(M) x 128(F), BK=64, 512 threads = 8 waves (4M x 2N), dbuf LDS 128KiB.
// (unchanged from R2: 484 us, MfmaUtil 52.5%, 0 bank conflicts, verified)
__global__ __launch_bounds__(512, 2)
void gemm_gateup(const unsigned short* __restrict__ Xb,
                 const unsigned short* __restrict__ WgT,
                 const unsigned short* __restrict__ WuT,
                 const float* __restrict__ bg, const float* __restrict__ bu,
                 unsigned short* __restrict__ X3) {
    constexpr int K = 2048, F = 8192, BK = 64, NT = K / BK;
    extern __shared__ __align__(16) unsigned short lds[];  // 128 KiB dynamic
    unsigned short* const A0 = lds;          // [2][256*64]
    unsigned short* const G0 = lds + 32768;  // [2][128*64]
    unsigned short* const U0 = lds + 49152;  // [2][128*64]

    const int tid = threadIdx.x;
    const int lane = tid & 63;
    const int wave = tid >> 6;          // 0..7
    const int wm = (wave >> 1) * 64;    // 0,64,128,192
    const int wn = (wave & 1) * 64;     // 0,64
    const int l16 = lane & 15;
    const int quad = lane >> 4;

    const int m0 = blockIdx.x * 256;
    const int n0 = blockIdx.y * 128;

    const unsigned short* Ag = Xb + (size_t)m0 * K;
    const unsigned short* Gg = WgT + (size_t)n0 * K;
    const unsigned short* Ug = WuT + (size_t)n0 * K;

    // staging: one unit = 128 rows x 64 k = 1024 chunks of 16B; 512 threads x 2.
    // LDS dest linear in chunk id (global_load_lds rule); global source column
    // carries the swizzle: col = (pos ^ (row&7)).
    int srow[2], soff[2];
#pragma unroll
    for (int j = 0; j < 2; ++j) {
        const int c = tid + j * 512;
        srow[j] = c >> 3;
        soff[j] = ((c & 7) ^ (srow[j] & 7)) * 8;
    }
    const int dst0 = tid * 8, dst1 = (tid + 512) * 8;

#define STAGE(gptr, lbase, kk, roff)                                                        \
    do {                                                                                    \
        gload16((gptr) + (size_t)(srow[0] + (roff)) * K + (kk) + soff[0], (lbase) + dst0);  \
        gload16((gptr) + (size_t)(srow[1] + (roff)) * K + (kk) + soff[1], (lbase) + dst1);  \
    } while (0)

    f32x4 accg[4][4] = {};
    f32x4 accu[4][4] = {};
    bf16x8 af[4], bfr[4];

    // prologue: tile 0 -> buf 0 (units: A-m0, A-m1, Bg, Bu)
    STAGE(Ag, A0, 0, 0);
    STAGE(Ag, A0 + 8192, 0, 128);
    STAGE(Gg, G0, 0, 0);
    STAGE(Ug, U0, 0, 0);
    ASM_VMCNT2;  // A + Bg done; Bu(0) may still fly (first read is ph1)
    __builtin_amdgcn_s_barrier();
    __builtin_amdgcn_sched_barrier(0);

    for (int t = 0; t < NT; ++t) {
        const int p = t & 1, q = p ^ 1;
        const unsigned short* Ap = A0 + p * 16384;
        const unsigned short* Gp = G0 + p * 8192;
        const unsigned short* Up = U0 + p * 8192;
        unsigned short* const Aq = A0 + q * 16384;
        unsigned short* const Gq = G0 + q * 8192;
        unsigned short* const Uq = U0 + q * 8192;
        const int kn = (t + 1) * BK;
        const bool pf = (t + 1 < NT);  // block-uniform

        // ---- ph0: gate, k-half 0 ; stage A-m0(t+1) ----
        ld_frag4(Ap, wm, 0, l16, quad, af);
        ld_frag4(Gp, wn, 0, l16, quad, bfr);
        if (pf) STAGE(Ag, Aq, kn, 0);
        __builtin_amdgcn_s_barrier();
        ASM_LGKM0;
        __builtin_amdgcn_sched_barrier(0);  // rule #18: pin MFMA after the wait
        mfma16x(af, bfr, accg);
        if (pf) {
            ASM_VMCNT2;  // Bu(t) done (read in ph1); A-m0(t+1) stays in flight
        } else {
            ASM_VMCNT0;  // last tile: nothing staged this phase -> drain Bu fully
        }
        __builtin_amdgcn_s_barrier();
        __builtin_amdgcn_sched_barrier(0);

        // ---- ph1: up, k-half 0 (af reused) ; stage A-m1(t+1) ----
        ld_frag4(Up, wn, 0, l16, quad, bfr);
        if (pf) STAGE(Ag, Aq + 8192, kn, 128);
        __builtin_amdgcn_s_barrier();
        ASM_LGKM0;
        __builtin_amdgcn_sched_barrier(0);
        mfma16x(af, bfr, accu);
        __builtin_amdgcn_s_barrier();

        // ---- ph2: gate, k-half 1 ; stage Bg(t+1) ----
        ld_frag4(Ap, wm, 1, l16, quad, af);
        ld_frag4(Gp, wn, 1, l16, quad, bfr);
        if (pf) STAGE(Gg, Gq, kn, 0);
        __builtin_amdgcn_s_barrier();
        ASM_LGKM0;
        __builtin_amdgcn_sched_barrier(0);
        mfma16x(af, bfr, accg);
        __builtin_amdgcn_s_barrier();

        // ---- ph3: up, k-half 1 ; stage Bu(t+1) ----
        ld_frag4(Up, wn, 1, l16, quad, bfr);
        if (pf) STAGE(Ug, Uq, kn, 0);
        __builtin_amdgcn_s_barrier();
        ASM_LGKM0;
        __builtin_amdgcn_sched_barrier(0);
        mfma16x(af, bfr, accu);
        ASM_VMCNT2;  // A(t+1)+Bg(t+1) done (read in ph0); Bu(t+1) stays in flight
        __builtin_amdgcn_s_barrier();
        __builtin_amdgcn_sched_barrier(0);
    }
#undef STAGE

    // epilogue: C/D layout col = lane&15, row = quad*4 + reg  [m89/m91-verified]
#pragma unroll
    for (int j = 0; j < 4; ++j) {
        const int col = n0 + wn + j * 16 + l16;
        const float bgv = bg[col];
        const float buv = bu[col];
#pragma unroll
        for (int i = 0; i < 4; ++i) {
            const int rowb = m0 + wm + i * 16 + quad * 4;
#pragma unroll
            for (int r = 0; r < 4; ++r) {
                float g = accg[i][j][r] + bgv;
                float u = accu[i][j][r] + buv;
                g = g > 0.f ? g : 0.f;
                X3[(size_t)(rowb + r) * F + col] = f2bf(g * u);
            }
        }
    }
}

// ---------------- down GEMM: out = X3@WdT^T + bd, fp32 out ------------------
// Tile 256(M) x 128(N), BK=64, 512 threads = 8 waves (4M x 2N).
// TRIPLE-buffered LDS (3 x 48 KiB = 144 KiB <= 160): only 2 operands per tile,
// so unlike gateup a 3rd buffer fits -> prefetch 2 K-tiles ahead. One counted
// vmcnt(6) per tile drains exactly tile t+1's 6 loads while tile t+2's 6 stay
// airborne across the whole next tile (~full K-step of latency cover).
// FIFO accounting (6 loads/tile/thread, in-order retire):
//   end of tile t: in-flight <= 12 = {t+1's 6, t+2's 6}; vmcnt(6) drains t+1's.
//   tail (t+2 >= NT, nothing staged this tile): vmcnt(0)  [R1 lesson].
// Write-after-read: STAGE target buf (t+2)%3 == (t-1)%3, last read before the
// end-of-tile-(t-1) barrier; STAGE issues after it.
__global__ __launch_bounds__(512, 2)
void gemm_down(const unsigned short* __restrict__ X3,
               const unsigned short* __restrict__ WdT,
               const float* __restrict__ bd, float* __restrict__ out) {
    constexpr int K = 8192, N = 2048, BK = 64, NT = K / BK;  // NT = 128
    extern __shared__ __align__(16) unsigned short lds[];    // 144 KiB dynamic
    // buffer b: A = lds + b*24576 (256x64), B = lds + b*24576 + 16384 (128x64)
#define ABUF(b) (lds + (b) * 24576)
#define BBUF(b) (lds + (b) * 24576 + 16384)

    const int tid = threadIdx.x;
    const int lane = tid & 63;
    const int wave = tid >> 6;          // 0..7
    const int wm = (wave >> 1) * 64;    // 0,64,128,192
    const int wn = (wave & 1) * 64;     // 0,64
    const int l16 = lane & 15;
    const int quad = lane >> 4;

    const int m0 = blockIdx.x * 256;
    const int n0 = blockIdx.y * 128;

    const unsigned short* Ag = X3 + (size_t)m0 * K;
    const unsigned short* Bg = WdT + (size_t)n0 * K;

    int srow[2], soff[2];
#pragma unroll
    for (int j = 0; j < 2; ++j) {
        const int c = tid + j * 512;
        srow[j] = c >> 3;
        soff[j] = ((c & 7) ^ (srow[j] & 7)) * 8;
    }
    const int dst0 = tid * 8, dst1 = (tid + 512) * 8;

#define STAGE(gptr, lbase, kk, roff)                                                        \
    do {                                                                                    \
        gload16((gptr) + (size_t)(srow[0] + (roff)) * K + (kk) + soff[0], (lbase) + dst0);  \
        gload16((gptr) + (size_t)(srow[1] + (roff)) * K + (kk) + soff[1], (lbase) + dst1);  \
    } while (0)

    f32x4 acc[4][4] = {};
    bf16x8 af[4], bfr[4];

    // prologue: stage tiles 0 and 1 (NT >= 2)
    STAGE(Ag, ABUF(0), 0, 0);
    STAGE(Ag, ABUF(0) + 8192, 0, 128);
    STAGE(Bg, BBUF(0), 0, 0);
    STAGE(Ag, ABUF(1), BK, 0);
    STAGE(Ag, ABUF(1) + 8192, BK, 128);
    STAGE(Bg, BBUF(1), BK, 0);
    ASM_VMCNT6;  // tile0's 6 loads drained; tile1's 6 stay in flight
    __builtin_amdgcn_s_barrier();
    __builtin_amdgcn_sched_barrier(0);

    for (int t = 0; t < NT; ++t) {
        const unsigned short* Ap = ABUF(t % 3);
        const unsigned short* Bp = BBUF(t % 3);
        const int qb = (t + 2) % 3;
        const int kn = (t + 2) * BK;
        const bool pf = (t + 2 < NT);  // block-uniform

        // ---- ph0: k-half 0 ; stage A(t+2) ----
        ld_frag4(Ap, wm, 0, l16, quad, af);
        ld_frag4(Bp, wn, 0, l16, quad, bfr);
        if (pf) {
            STAGE(Ag, ABUF(qb), kn, 0);
            STAGE(Ag, ABUF(qb) + 8192, kn, 128);
        }
        __builtin_amdgcn_s_barrier();
        ASM_LGKM0;
        __builtin_amdgcn_sched_barrier(0);  // rule #18
        mfma16x(af, bfr, acc);
        __builtin_amdgcn_s_barrier();

        // ---- ph1: k-half 1 ; stage B(t+2) ----
        ld_frag4(Ap, wm, 1, l16, quad, af);
        ld_frag4(Bp, wn, 1, l16, quad, bfr);
        if (pf) STAGE(Bg, BBUF(qb), kn, 0);
        __builtin_amdgcn_s_barrier();
        ASM_LGKM0;
        __builtin_amdgcn_sched_barrier(0);
        mfma16x(af, bfr, acc);
        if (pf) {
            ASM_VMCNT6;  // drain tile t+1's 6; tile t+2's 6 stay airborne
        } else {
            ASM_VMCNT0;  // tail: nothing staged this tile -> full drain
        }
        __builtin_amdgcn_s_barrier();
        __builtin_amdgcn_sched_barrier(0);
    }
#undef STAGE
#undef ABUF
#undef BBUF

    // epilogue: C/D layout col = lane&15, row = quad*4 + reg
#pragma unroll
    for (int j = 0; j < 4; ++j) {
        const int col = n0 + wn + j * 16 + l16;
        const float bdv = bd[col];
#pragma unroll
        for (int i = 0; i < 4; ++i) {
            const int rowb = m0 + wm + i * 16 + quad * 4;
#pragma unroll
            for (int r = 0; r < 4; ++r)
                out[(size_t)(rowb + r) * N + col] = acc[i][j][r] + bdv;
        }
    }
}

extern "C" void kernel_launch(void* const* d_in, const int* in_sizes, int n_in,
                              void* d_out, int out_size, void* d_ws, size_t ws_size,
                              hipStream_t stream) {
    const float* x1      = (const float*)d_in[0];
    const float* w_gate  = (const float*)d_in[1];
    const float* b_gate  = (const float*)d_in[2];
    const float* a_gate  = (const float*)d_in[3];
    const float* lb_gate = (const float*)d_in[4];
    const float* w_up    = (const float*)d_in[5];
    const float* b_up    = (const float*)d_in[6];
    const float* a_up    = (const float*)d_in[7];
    const float* lb_up   = (const float*)d_in[8];
    const float* w_down  = (const float*)d_in[9];
    const float* b_down  = (const float*)d_in[10];
    const float* a_down  = (const float*)d_in[11];
    const float* lb_down = (const float*)d_in[12];

    constexpr int M = 8192, D = 2048, F = 8192;

    // one-time: allow big dynamic LDS (gfx950 has 160 KiB/CU)
    static bool attr_set = false;
    if (!attr_set) {
        (void)hipFuncSetAttribute((const void*)gemm_gateup,
                                  hipFuncAttributeMaxDynamicSharedMemorySize, 131072);
        (void)hipFuncSetAttribute((const void*)gemm_down,
                                  hipFuncAttributeMaxDynamicSharedMemorySize, 147456);
        attr_set = true;
    }

    // workspace layout (256 MiB total)
    char* ws = (char*)d_ws;
    unsigned short* Xb  = (unsigned short*)ws;                     // [M,D]  bf16  32 MiB
    unsigned short* WgT = (unsigned short*)(ws + 33554432ULL);     // [F,D]  bf16  32 MiB
    unsigned short* WuT = (unsigned short*)(ws + 67108864ULL);     // [F,D]  bf16  32 MiB
    unsigned short* WdT = (unsigned short*)(ws + 100663296ULL);    // [D,F]  bf16  32 MiB
    unsigned short* X3  = (unsigned short*)(ws + 134217728ULL);    // [M,F]  bf16 128 MiB

    cast_x_kernel<<<dim3((M * D) / 4 / 256), dim3(256), 0, stream>>>(
        (const float4*)x1, (ushort4*)Xb);
    prep_wT<<<dim3(D / 64, F / 64), dim3(256), 0, stream>>>(w_gate, a_gate, lb_gate, WgT, D, F);
    prep_wT<<<dim3(D / 64, F / 64), dim3(256), 0, stream>>>(w_up, a_up, lb_up, WuT, D, F);
    prep_wT<<<dim3(F / 64, D / 64), dim3(256), 0, stream>>>(w_down, a_down, lb_down, WdT, F, D);

    gemm_gateup<<<dim3(M / 256, F / 128), dim3(512), 131072, stream>>>(
        Xb, WgT, WuT, b_gate, b_up, X3);
    gemm_down<<<dim3(M / 256, D / 128), dim3(512), 147456, stream>>>(
        X3, WdT, b_down, (float*)d_out);
}

// Round 4
// 965.150 us; speedup vs baseline: 1.1523x; 1.0479x over previous
//
#include <hip/hip_runtime.h>

// bf16 storage type = ushort (raw bits); avoids hip_bf16.h dependency.
typedef __bf16 bf16x8 __attribute__((ext_vector_type(8)));
typedef float f32x4 __attribute__((ext_vector_type(4)));

#define MFMA16(a, b, c) __builtin_amdgcn_mfma_f32_16x16x32_bf16((a), (b), (c), 0, 0, 0)

__device__ __forceinline__ unsigned short f2bf(float f) {
    // round-to-nearest-even bf16 (finite inputs)
    unsigned int u = __float_as_uint(f);
    u += 0x7fffu + ((u >> 16) & 1u);
    return (unsigned short)(u >> 16);
}

__device__ __forceinline__ void gload16(const unsigned short* g, unsigned short* l) {
    // async global->LDS, 16B per lane; LDS dest = wave-uniform base + lane*16
    __builtin_amdgcn_global_load_lds(
        (__attribute__((address_space(1))) void*)(void*)g,
        (__attribute__((address_space(3))) void*)(void*)l,
        16, 0, 0);
}

// BK=64 tile: rows x 64 bf16 = 128 B/row = 8 chunks of 16 B.
// Swizzle: global chunk (r,c) stored at LDS position (r, c ^ (r&7)).
// Reader at fixed (k-half, quad) spreads uniformly over all 8 bank-quads
// across 16 consecutive rows -> conflict-free (verified: 0 conflicts).

// frag load: 4x ds_read_b128 from a swizzled [rows][64] bf16 tile
__device__ __forceinline__ void ld_frag4(const unsigned short* base, int w0, int h,
                                         int l16, int quad, bf16x8* f) {
#pragma unroll
    for (int i = 0; i < 4; ++i) {
        const int r = w0 + i * 16 + l16;
        f[i] = *(const bf16x8*)(base + r * 64 + (((h * 4 + quad) ^ (r & 7)) * 8));
    }
}

__device__ __forceinline__ void mfma16x(const bf16x8* af, const bf16x8* bf, f32x4 (*acc)[4]) {
    __builtin_amdgcn_s_setprio(1);  // T5: favor MFMA-entering waves
#pragma unroll
    for (int i = 0; i < 4; ++i)
#pragma unroll
        for (int j = 0; j < 4; ++j) acc[i][j] = MFMA16(af[i], bf[j], acc[i][j]);
    __builtin_amdgcn_s_setprio(0);
}

#define ASM_VMCNT6 asm volatile("s_waitcnt vmcnt(6)" ::: "memory")
#define ASM_VMCNT2 asm volatile("s_waitcnt vmcnt(2)" ::: "memory")
#define ASM_VMCNT0 asm volatile("s_waitcnt vmcnt(0)" ::: "memory")
#define ASM_LGKM0  asm volatile("s_waitcnt lgkmcnt(0)" ::: "memory")
#define SBAR __builtin_amdgcn_s_barrier()
#define SCHED0 __builtin_amdgcn_sched_barrier(0)

// ---------------- prep: x fp32 -> bf16 ----------------
__global__ void cast_x_kernel(const float4* __restrict__ x, ushort4* __restrict__ xb) {
    const size_t i = (size_t)blockIdx.x * 256 + threadIdx.x;
    const float4 v = x[i];
    ushort4 o;
    o.x = f2bf(v.x); o.y = f2bf(v.y); o.z = f2bf(v.z); o.w = f2bf(v.w);
    xb[i] = o;
}

// ---------------- prep: WT[n,k] = W[k,n] + sum_r A[k,r]*B2[r,n], bf16 out ----
// Vectorized (G13): float4 W/A/B2 loads, ushort4 WT stores. LDS transpose via
// [64][65] pad; all tile accesses <=2-way bank alias (free).
__global__ void prep_wT(const float* __restrict__ W, const float* __restrict__ A,
                        const float* __restrict__ B2, unsigned short* __restrict__ WT,
                        const int K, const int N) {
    __shared__ float tile[64][65];
    __shared__ float As[64][16];
    __shared__ float Bs[16][64];
    const int t = threadIdx.x;         // 256 threads
    const int k0 = blockIdx.x * 64;
    const int n0 = blockIdx.y * 64;

    {   // As: 64x16 = 256 float4 ; Bs: 16x64 = 256 float4
        const int ar = t >> 2, aq = (t & 3) * 4;
        *(float4*)&As[ar][aq] = *(const float4*)&A[(size_t)(k0 + ar) * 16 + aq];
        const int br = t >> 4, bc = (t & 15) * 4;
        *(float4*)&Bs[br][bc] = *(const float4*)&B2[(size_t)br * N + n0 + bc];
    }
    __syncthreads();

    const int c4 = (t & 15) * 4;       // 4 consecutive n-cols per thread
    const int r0 = t >> 4;             // 16 rows per pass
    for (int rr = 0; rr < 64; rr += 16) {
        const int r = rr + r0;
        float4 v = *(const float4*)&W[(size_t)(k0 + r) * N + n0 + c4];
#pragma unroll
        for (int q = 0; q < 16; ++q) {
            const float a = As[r][q];
            v.x += a * Bs[q][c4];     v.y += a * Bs[q][c4 + 1];
            v.z += a * Bs[q][c4 + 2]; v.w += a * Bs[q][c4 + 3];
        }
        tile[r][c4] = v.x; tile[r][c4 + 1] = v.y;
        tile[r][c4 + 2] = v.z; tile[r][c4 + 3] = v.w;
    }
    __syncthreads();

    // write transposed: thread covers 4 consecutive k per n-row
    for (int rr = 0; rr < 64; rr += 16) {
        const int r = rr + r0;         // n index
        ushort4 o;
        o.x = f2bf(tile[c4][r]);     o.y = f2bf(tile[c4 + 1][r]);
        o.z = f2bf(tile[c4 + 2][r]); o.w = f2bf(tile[c4 + 3][r]);
        *(ushort4*)&WT[(size_t)(n0 + r) * K + k0 + c4] = o;
    }
}

// ---------------- fused gate+up GEMM, 4-phase counted-vmcnt schedule ---------
// Tile 256(M) x 128(F), BK=64, 512 threads = 8 waves (4M x 2N), dbuf LDS 128KiB.
// R4: minimal-barrier schedule. Dependency-derived sync = 2 barrier+vmcnt
// pairs per K-tile (was 8 barriers):
//   - end-ph0: vmcnt(2)+barrier  -> drains Bu(t) before ph1's Up reads.
//   - end-ph3: vmcnt(2)+barrier  -> drains A0,A1,Bg(t+1) before ph0(t+1).
//   ph1/ph2/ph3 entry reads are resident data (drained+barriered earlier);
//   staging into buffer q is WAR vs tile t-1, whose last read precedes the
//   end-ph3(t-1) barrier. Last tile: end-ph0 must be vmcnt(0) (R1 lesson).
__global__ __launch_bounds__(512, 2)
void gemm_gateup(const unsigned short* __restrict__ Xb,
                 const unsigned short* __restrict__ WgT,
                 const unsigned short* __restrict__ WuT,
                 const float* __restrict__ bg, const float* __restrict__ bu,
                 unsigned short* __restrict__ X3) {
    constexpr int K = 2048, F = 8192, BK = 64, NT = K / BK;
    extern __shared__ __align__(16) unsigned short lds[];  // 128 KiB dynamic
    unsigned short* const A0 = lds;          // [2][256*64]
    unsigned short* const G0 = lds + 32768;  // [2][128*64]
    unsigned short* const U0 = lds + 49152;  // [2][128*64]

    const int tid = threadIdx.x;
    const int lane = tid & 63;
    const int wave = tid >> 6;          // 0..7
    const int wm = (wave >> 1) * 64;    // 0,64,128,192
    const int wn = (wave & 1) * 64;     // 0,64
    const int l16 = lane & 15;
    const int quad = lane >> 4;

    const int m0 = blockIdx.x * 256;
    const int n0 = blockIdx.y * 128;

    const unsigned short* Ag = Xb + (size_t)m0 * K;
    const unsigned short* Gg = WgT + (size_t)n0 * K;
    const unsigned short* Ug = WuT + (size_t)n0 * K;

    // staging: one unit = 128 rows x 64 k = 1024 chunks of 16B; 512 threads x 2.
    int srow[2], soff[2];
#pragma unroll
    for (int j = 0; j < 2; ++j) {
        const int c = tid + j * 512;
        srow[j] = c >> 3;
        soff[j] = ((c & 7) ^ (srow[j] & 7)) * 8;
    }
    const int dst0 = tid * 8, dst1 = (tid + 512) * 8;

#define STAGE(gptr, lbase, kk, roff)                                                        \
    do {                                                                                    \
        gload16((gptr) + (size_t)(srow[0] + (roff)) * K + (kk) + soff[0], (lbase) + dst0);  \
        gload16((gptr) + (size_t)(srow[1] + (roff)) * K + (kk) + soff[1], (lbase) + dst1);  \
    } while (0)

    f32x4 accg[4][4] = {};
    f32x4 accu[4][4] = {};
    bf16x8 af[4], bfr[4];

    // prologue: tile 0 -> buf 0 (units: A-m0, A-m1, Bg, Bu)
    STAGE(Ag, A0, 0, 0);
    STAGE(Ag, A0 + 8192, 0, 128);
    STAGE(Gg, G0, 0, 0);
    STAGE(Ug, U0, 0, 0);
    ASM_VMCNT2;  // A + Bg done; Bu(0) may still fly (first read is ph1)
    SBAR;
    SCHED0;

    for (int t = 0; t < NT; ++t) {
        const int p = t & 1, q = p ^ 1;
        const unsigned short* Ap = A0 + p * 16384;
        const unsigned short* Gp = G0 + p * 8192;
        const unsigned short* Up = U0 + p * 8192;
        unsigned short* const Aq = A0 + q * 16384;
        unsigned short* const Gq = G0 + q * 8192;
        unsigned short* const Uq = U0 + q * 8192;
        const int kn = (t + 1) * BK;
        const bool pf = (t + 1 < NT);  // block-uniform

        // ---- ph0: gate, k-half 0 ; stage A-m0(t+1) ----
        ld_frag4(Ap, wm, 0, l16, quad, af);
        ld_frag4(Gp, wn, 0, l16, quad, bfr);
        if (pf) STAGE(Ag, Aq, kn, 0);
        ASM_LGKM0;
        SCHED0;  // rule #18: pin MFMA after the wait
        mfma16x(af, bfr, accg);
        if (pf) {
            ASM_VMCNT2;  // drain Bu(t); A-m0(t+1) stays in flight
        } else {
            ASM_VMCNT0;  // last tile: nothing staged this phase -> drain Bu fully
        }
        SBAR;            // all waves' Bu(t) drained before any Up read
        SCHED0;

        // ---- ph1: up, k-half 0 (af reused) ; stage A-m1(t+1) ----
        ld_frag4(Up, wn, 0, l16, quad, bfr);
        if (pf) STAGE(Ag, Aq + 8192, kn, 128);
        ASM_LGKM0;
        SCHED0;
        mfma16x(af, bfr, accu);
        // no barrier: ph2 reads resident tile-t data

        // ---- ph2: gate, k-half 1 ; stage Bg(t+1) ----
        ld_frag4(Ap, wm, 1, l16, quad, af);
        ld_frag4(Gp, wn, 1, l16, quad, bfr);
        if (pf) STAGE(Gg, Gq, kn, 0);
        ASM_LGKM0;
        SCHED0;
        mfma16x(af, bfr, accg);
        // no barrier: ph3 reads resident tile-t data

        // ---- ph3: up, k-half 1 ; stage Bu(t+1) ----
        ld_frag4(Up, wn, 1, l16, quad, bfr);
        if (pf) STAGE(Ug, Uq, kn, 0);
        ASM_LGKM0;
        SCHED0;
        mfma16x(af, bfr, accu);
        ASM_VMCNT2;  // drain A0,A1,Bg(t+1); Bu(t+1) stays in flight
        SBAR;
        SCHED0;
    }
#undef STAGE

    // epilogue: C/D layout col = lane&15, row = quad*4 + reg  [m89/m91-verified]
#pragma unroll
    for (int j = 0; j < 4; ++j) {
        const int col = n0 + wn + j * 16 + l16;
        const float bgv = bg[col];
        const float buv = bu[col];
#pragma unroll
        for (int i = 0; i < 4; ++i) {
            const int rowb = m0 + wm + i * 16 + quad * 4;
#pragma unroll
            for (int r = 0; r < 4; ++r) {
                float g = accg[i][j][r] + bgv;
                float u = accu[i][j][r] + buv;
                g = g > 0.f ? g : 0.f;
                X3[(size_t)(rowb + r) * F + col] = f2bf(g * u);
            }
        }
    }
}

// ---------------- down GEMM: out = X3@WdT^T + bd, fp32 out ------------------
// Tile 256(M) x 128(N), BK=64, 512 threads, TRIPLE-buffered LDS (144 KiB),
// prefetch 2 K-tiles ahead. R4: minimal-barrier -> ONE barrier+vmcnt per tile
// (was 4 barriers): ph1 reads resident tile-t data; staging WAR vs tile t-1
// protected by end-of-tile-(t-1) barrier. End-of-tile vmcnt(6) drains t+1's
// 6 loads, t+2's 6 stay airborne; tail (nothing staged): vmcnt(0).
__global__ __launch_bounds__(512, 2)
void gemm_down(const unsigned short* __restrict__ X3,
               const unsigned short* __restrict__ WdT,
               const float* __restrict__ bd, float* __restrict__ out) {
    constexpr int K = 8192, N = 2048, BK = 64, NT = K / BK;  // NT = 128
    extern __shared__ __align__(16) unsigned short lds[];    // 144 KiB dynamic
#define ABUF(b) (lds + (b) * 24576)
#define BBUF(b) (lds + (b) * 24576 + 16384)

    const int tid = threadIdx.x;
    const int lane = tid & 63;
    const int wave = tid >> 6;          // 0..7
    const int wm = (wave >> 1) * 64;    // 0,64,128,192
    const int wn = (wave & 1) * 64;     // 0,64
    const int l16 = lane & 15;
    const int quad = lane >> 4;

    const int m0 = blockIdx.x * 256;
    const int n0 = blockIdx.y * 128;

    const unsigned short* Ag = X3 + (size_t)m0 * K;
    const unsigned short* Bg = WdT + (size_t)n0 * K;

    int srow[2], soff[2];
#pragma unroll
    for (int j = 0; j < 2; ++j) {
        const int c = tid + j * 512;
        srow[j] = c >> 3;
        soff[j] = ((c & 7) ^ (srow[j] & 7)) * 8;
    }
    const int dst0 = tid * 8, dst1 = (tid + 512) * 8;

#define STAGE(gptr, lbase, kk, roff)                                                        \
    do {                                                                                    \
        gload16((gptr) + (size_t)(srow[0] + (roff)) * K + (kk) + soff[0], (lbase) + dst0);  \
        gload16((gptr) + (size_t)(srow[1] + (roff)) * K + (kk) + soff[1], (lbase) + dst1);  \
    } while (0)

    f32x4 acc[4][4] = {};
    bf16x8 af[4], bfr[4];

    // prologue: stage tiles 0 and 1 (NT >= 2)
    STAGE(Ag, ABUF(0), 0, 0);
    STAGE(Ag, ABUF(0) + 8192, 0, 128);
    STAGE(Bg, BBUF(0), 0, 0);
    STAGE(Ag, ABUF(1), BK, 0);
    STAGE(Ag, ABUF(1) + 8192, BK, 128);
    STAGE(Bg, BBUF(1), BK, 0);
    ASM_VMCNT6;  // tile0's 6 loads drained; tile1's 6 stay in flight
    SBAR;
    SCHED0;

    for (int t = 0; t < NT; ++t) {
        const unsigned short* Ap = ABUF(t % 3);
        const unsigned short* Bp = BBUF(t % 3);
        const int qb = (t + 2) % 3;
        const int kn = (t + 2) * BK;
        const bool pf = (t + 2 < NT);  // block-uniform

        // ---- ph0: k-half 0 ; stage A(t+2) ----
        ld_frag4(Ap, wm, 0, l16, quad, af);
        ld_frag4(Bp, wn, 0, l16, quad, bfr);
        if (pf) {
            STAGE(Ag, ABUF(qb), kn, 0);
            STAGE(Ag, ABUF(qb) + 8192, kn, 128);
        }
        ASM_LGKM0;
        SCHED0;  // rule #18
        mfma16x(af, bfr, acc);
        // no barrier: ph1 reads resident tile-t data

        // ---- ph1: k-half 1 ; stage B(t+2) ----
        ld_frag4(Ap, wm, 1, l16, quad, af);
        ld_frag4(Bp, wn, 1, l16, quad, bfr);
        if (pf) STAGE(Bg, BBUF(qb), kn, 0);
        ASM_LGKM0;
        SCHED0;
        mfma16x(af, bfr, acc);
        if (pf) {
            ASM_VMCNT6;  // drain tile t+1's 6; tile t+2's 6 stay airborne
        } else {
            ASM_VMCNT0;  // tail: nothing staged this tile -> full drain
        }
        SBAR;
        SCHED0;
    }
#undef STAGE
#undef ABUF
#undef BBUF

    // epilogue: C/D layout col = lane&15, row = quad*4 + reg
#pragma unroll
    for (int j = 0; j < 4; ++j) {
        const int col = n0 + wn + j * 16 + l16;
        const float bdv = bd[col];
#pragma unroll
        for (int i = 0; i < 4; ++i) {
            const int rowb = m0 + wm + i * 16 + quad * 4;
#pragma unroll
            for (int r = 0; r < 4; ++r)
                out[(size_t)(rowb + r) * N + col] = acc[i][j][r] + bdv;
        }
    }
}

extern "C" void kernel_launch(void* const* d_in, const int* in_sizes, int n_in,
                              void* d_out, int out_size, void* d_ws, size_t ws_size,
                              hipStream_t stream) {
    const float* x1      = (const float*)d_in[0];
    const float* w_gate  = (const float*)d_in[1];
    const float* b_gate  = (const float*)d_in[2];
    const float* a_gate  = (const float*)d_in[3];
    const float* lb_gate = (const float*)d_in[4];
    const float* w_up    = (const float*)d_in[5];
    const float* b_up    = (const float*)d_in[6];
    const float* a_up    = (const float*)d_in[7];
    const float* lb_up   = (const float*)d_in[8];
    const float* w_down  = (const float*)d_in[9];
    const float* b_down  = (const float*)d_in[10];
    const float* a_down  = (const float*)d_in[11];
    const float* lb_down = (const float*)d_in[12];

    constexpr int M = 8192, D = 2048, F = 8192;

    // one-time: allow big dynamic LDS (gfx950 has 160 KiB/CU)
    static bool attr_set = false;
    if (!attr_set) {
        (void)hipFuncSetAttribute((const void*)gemm_gateup,
                                  hipFuncAttributeMaxDynamicSharedMemorySize, 131072);
        (void)hipFuncSetAttribute((const void*)gemm_down,
                                  hipFuncAttributeMaxDynamicSharedMemorySize, 147456);
        attr_set = true;
    }

    // workspace layout (256 MiB total)
    char* ws = (char*)d_ws;
    unsigned short* Xb  = (unsigned short*)ws;                     // [M,D]  bf16  32 MiB
    unsigned short* WgT = (unsigned short*)(ws + 33554432ULL);     // [F,D]  bf16  32 MiB
    unsigned short* WuT = (unsigned short*)(ws + 67108864ULL);     // [F,D]  bf16  32 MiB
    unsigned short* WdT = (unsigned short*)(ws + 100663296ULL);    // [D,F]  bf16  32 MiB
    unsigned short* X3  = (unsigned short*)(ws + 134217728ULL);    // [M,F]  bf16 128 MiB

    cast_x_kernel<<<dim3((M * D) / 4 / 256), dim3(256), 0, stream>>>(
        (const float4*)x1, (ushort4*)Xb);
    prep_wT<<<dim3(D / 64, F / 64), dim3(256), 0, stream>>>(w_gate, a_gate, lb_gate, WgT, D, F);
    prep_wT<<<dim3(D / 64, F / 64), dim3(256), 0, stream>>>(w_up, a_up, lb_up, WuT, D, F);
    prep_wT<<<dim3(F / 64, D / 64), dim3(256), 0, stream>>>(w_down, a_down, lb_down, WdT, F, D);

    gemm_gateup<<<dim3(M / 256, F / 128), dim3(512), 131072, stream>>>(
        Xb, WgT, WuT, b_gate, b_up, X3);
    gemm_down<<<dim3(M / 256, D / 128), dim3(512), 147456, stream>>>(
        X3, WdT, b_down, (float*)d_out);
}